// Round 2
// 207.809 us; speedup vs baseline: 1.0184x; 1.0184x over previous
//
#include <hip/hip_runtime.h>
#include <math.h>

// Problem constants (fixed by the reference):
// B=2, N=131072 (=2^17), K=9, P=4, D=4, S=1, CI=8, CO=8
#define N_PTS 131072
#define KNB   9
#define PD    16          // P*D*S = 16 (p,d) cells per point
#define CIN   8
#define COUT  8
#define PTS_PER_BLK 16    // points per block (256 threads / 16 pd-threads)
#define THREADS 256
#define AMP_STRIDE 68     // 64 + 4 pad: 272 B = 17*16 B -> float4-aligned, pd lanes 2-way (free)

// Native clang vector (NOT HIP_vector_type) — required by nontemporal builtins.
typedef float f32x4 __attribute__((ext_vector_type(4)));

__global__ __launch_bounds__(THREADS) void polnormal_kernel(
    const float* __restrict__ x,      // (B, N, CI)
    const float* __restrict__ dx,     // (B, N, K)
    const float* __restrict__ dy,     // (B, N, K)
    const int*   __restrict__ adj,    // (N, K)
    const float* __restrict__ phis,  // (P,)
    const float* __restrict__ dists, // (D,)
    const float* __restrict__ sigma, // (S,) = (1,)
    const float* __restrict__ amp,   // (P, D, S, CI, CO) = (pd, c, o)
    float*       __restrict__ out)   // (B, N, P, D, S, CO)
{
    __shared__ float s_dx[PTS_PER_BLK * KNB];
    __shared__ float s_dy[PTS_PER_BLK * KNB];
    __shared__ float s_x[PTS_PER_BLK * KNB * CIN];   // [i][k][c]
    __shared__ float s_amp[PD * AMP_STRIDE];

    const int  tid    = threadIdx.x;
    const long base_g = (long)blockIdx.x * PTS_PER_BLK;   // flattened (b,n); 16 | N so no b-straddle
    const int  b      = (int)(base_g >> 17);              // N = 2^17
    const int  base_n = (int)(base_g & (N_PTS - 1));

    // Stage dx/dy as float4, NON-TEMPORAL: stream-once data must not evict the
    // x rows we gather (x is the only data with reuse; keep L2 for it).
    // 144 floats each = 36 float4 per array; base offset 144*blk floats = 36*blk float4.
    if (tid < 36) {
        ((f32x4*)s_dx)[tid] =
            __builtin_nontemporal_load(&((const f32x4*)dx)[(long)blockIdx.x * 36 + tid]);
    } else if (tid < 72) {
        const int t = tid - 36;
        ((f32x4*)s_dy)[t] =
            __builtin_nontemporal_load(&((const f32x4*)dy)[(long)blockIdx.x * 36 + t]);
    }

    // Stage amplitudes (4 KB, hot in L1/L2 across all blocks): exactly one
    // float4 per thread. dst byte offset pd*272 + co*4 is 16B-aligned.
    {
        const int pd = tid >> 4;
        const int co = (tid & 15) << 2;
        *(f32x4*)&s_amp[pd * AMP_STRIDE + co] = ((const f32x4*)amp)[tid];
    }

    // Gather neighbor features straight from global adj (no s_adj staging, no
    // first barrier): 288 float4s, two threads share one adj element
    // (coalesced 128B wave reads). x rows are 32B-aligned.
    for (int t = tid; t < PTS_PER_BLK * KNB * 2; t += THREADS) {
        const int  pair = t >> 1;            // i*K + k
        const int  half = t & 1;
        const long row  = (long)adj[(long)base_n * KNB + pair];
        const f32x4* src = (const f32x4*)(x + ((long)b * N_PTS + row) * CIN);
        ((f32x4*)s_x)[pair * 2 + half] = src[half];
    }
    __syncthreads();   // single barrier: covers s_dx/s_dy/s_amp/s_x

    // One thread per (point i, pd cell).
    const int i  = tid >> 4;
    const int pd = tid & 15;
    const int p  = pd >> 2;
    const int d  = pd & 3;

    const float phi  = phis[p];
    const float dist = dists[d];
    float sn, cs;
    __sincosf(phi, &sn, &cs);
    const float mux = cs * dist;
    const float muy = sn * dist;

    float sig = fmaxf(sigma[0], 1e-10f);
    const float s2         = sig * sig;
    const float neg_inv2s2 = -0.5f / s2;
    const float norm       = rsqrtf(6.283185307179586f * s2);

    float wx[CIN];
#pragma unroll
    for (int c = 0; c < CIN; ++c) wx[c] = 0.0f;

#pragma unroll
    for (int k = 0; k < KNB; ++k) {
        const float ddx = s_dx[i * KNB + k] - mux;
        const float ddy = s_dy[i * KNB + k] - muy;
        const float r2  = ddx * ddx + ddy * ddy;
        const float w   = __expf(neg_inv2s2 * r2) * norm;
        const float* xr = &s_x[(i * KNB + k) * CIN];
#pragma unroll
        for (int c = 0; c < CIN; ++c) wx[c] += w * xr[c];
    }

    float acc[COUT];
#pragma unroll
    for (int o = 0; o < COUT; ++o) acc[o] = 0.0f;
#pragma unroll
    for (int c = 0; c < CIN; ++c) {
        const float wc = wx[c];
        const float* ar = &s_amp[pd * AMP_STRIDE + c * COUT];
#pragma unroll
        for (int o = 0; o < COUT; ++o) acc[o] += wc * ar[o];
    }

    // out[((g*16)+pd)*8 + o] : 32 B/thread, contiguous across pd-threads.
    // NON-TEMPORAL: 134 MB of pure streaming writes must not thrash L2.
    float* op = out + ((base_g + i) * PD + pd) * COUT;
    f32x4 lo = { acc[0], acc[1], acc[2], acc[3] };
    f32x4 hi = { acc[4], acc[5], acc[6], acc[7] };
    __builtin_nontemporal_store(lo, (f32x4*)op);
    __builtin_nontemporal_store(hi, (f32x4*)(op + 4));
}

extern "C" void kernel_launch(void* const* d_in, const int* in_sizes, int n_in,
                              void* d_out, int out_size, void* d_ws, size_t ws_size,
                              hipStream_t stream) {
    const float* x     = (const float*)d_in[0];
    const float* dx    = (const float*)d_in[1];
    const float* dy    = (const float*)d_in[2];
    const int*   adj   = (const int*)  d_in[3];
    const float* phis  = (const float*)d_in[4];
    const float* dists = (const float*)d_in[5];
    const float* sigma = (const float*)d_in[6];
    const float* amp   = (const float*)d_in[7];
    float* out = (float*)d_out;

    const int total_pts = 2 * N_PTS;                 // B*N = 262144
    const int grid = total_pts / PTS_PER_BLK;        // 16384 blocks
    polnormal_kernel<<<grid, THREADS, 0, stream>>>(x, dx, dy, adj, phis, dists,
                                                   sigma, amp, out);
}

// Round 3
// 201.156 us; speedup vs baseline: 1.0521x; 1.0331x over previous
//
#include <hip/hip_runtime.h>
#include <math.h>

// Problem constants (fixed by the reference):
// B=2, N=131072 (=2^17), K=9, P=4, D=4, S=1, CI=8, CO=8
#define N_PTS 131072
#define KNB   9
#define PD    16          // P*D*S = 16 (p,d) cells per point
#define CIN   8
#define COUT  8
#define PTS_PER_BLK 16    // points per block (256 threads / 16 pd-threads)
#define THREADS 256
#define AMP_STRIDE 68     // 64 + 4 pad: 272 B = 17*16 B -> float4-aligned, pd lanes 2-way (free)

// Native clang vectors (NOT HIP_vector_type) — required by nontemporal builtins,
// and f32x2 arithmetic encourages v_pk_fma_f32 (packed fp32: 2 FMA / instr slot).
typedef float f32x2 __attribute__((ext_vector_type(2)));
typedef float f32x4 __attribute__((ext_vector_type(4)));

#if __has_builtin(__builtin_amdgcn_exp2f)
#define EXP2F(v) __builtin_amdgcn_exp2f(v)
#else
#define EXP2F(v) exp2f(v)
#endif

__global__ __launch_bounds__(THREADS) void polnormal_kernel(
    const float* __restrict__ x,      // (B, N, CI)
    const float* __restrict__ dx,     // (B, N, K)
    const float* __restrict__ dy,     // (B, N, K)
    const int*   __restrict__ adj,    // (N, K)
    const float* __restrict__ phis,  // (P,)
    const float* __restrict__ dists, // (D,)
    const float* __restrict__ sigma, // (S,) = (1,)
    const float* __restrict__ amp,   // (P, D, S, CI, CO) = (pd, c, o)
    float*       __restrict__ out)   // (B, N, P, D, S, CO)
{
    __shared__ float s_dx[PTS_PER_BLK * KNB];
    __shared__ float s_dy[PTS_PER_BLK * KNB];
    __shared__ float s_x[PTS_PER_BLK * KNB * CIN];   // [i][k][c]
    __shared__ float s_amp[PD * AMP_STRIDE];

    const int  tid    = threadIdx.x;
    const long base_g = (long)blockIdx.x * PTS_PER_BLK;   // flattened (b,n); 16 | N so no b-straddle
    const int  b      = (int)(base_g >> 17);              // N = 2^17
    const int  base_n = (int)(base_g & (N_PTS - 1));

    // Stage dx/dy as float4, NON-TEMPORAL: stream-once data must not evict the
    // x rows we gather (x is the only data with reuse; keep L2 for it).
    if (tid < 36) {
        ((f32x4*)s_dx)[tid] =
            __builtin_nontemporal_load(&((const f32x4*)dx)[(long)blockIdx.x * 36 + tid]);
    } else if (tid < 72) {
        const int t = tid - 36;
        ((f32x4*)s_dy)[t] =
            __builtin_nontemporal_load(&((const f32x4*)dy)[(long)blockIdx.x * 36 + t]);
    }

    // Stage amplitudes (4 KB, hot in L2 across all blocks): one float4/thread.
    {
        const int pd = tid >> 4;
        const int co = (tid & 15) << 2;
        *(f32x4*)&s_amp[pd * AMP_STRIDE + co] = ((const f32x4*)amp)[tid];
    }

    // Gather neighbor features straight from global adj: 288 float4s, two
    // threads share one adj element (coalesced). x rows are 32B-aligned.
    for (int t = tid; t < PTS_PER_BLK * KNB * 2; t += THREADS) {
        const int  pair = t >> 1;            // i*K + k
        const int  half = t & 1;
        const long row  = (long)adj[(long)base_n * KNB + pair];
        const f32x4* src = (const f32x4*)(x + ((long)b * N_PTS + row) * CIN);
        ((f32x4*)s_x)[pair * 2 + half] = src[half];
    }
    __syncthreads();   // single barrier: covers s_dx/s_dy/s_amp/s_x

    // One thread per (point i, pd cell).
    const int i  = tid >> 4;
    const int pd = tid & 15;
    const int p  = pd >> 2;
    const int d  = pd & 3;

    const float phi  = phis[p];
    const float dist = dists[d];
    float sn, cs;
    __sincosf(phi, &sn, &cs);
    const float mux = cs * dist;
    const float muy = sn * dist;

    const float sig = fmaxf(sigma[0], 1e-10f);
    const float s2  = sig * sig;
    // w = norm * exp(-0.5 r2 / s2)  ==  exp2(c1 * r2 + c2)
    //   c1 = -0.5/s2 * log2(e),  c2 = log2(norm) = -0.5*log2(2*pi*s2)
    const float c1 = (-0.5f / s2) * 1.44269504088896340736f;
    const float c2 = -0.5f * __log2f(6.283185307179586f * s2);

    // wx as 4x float2 -> v_pk_fma_f32 candidates.
    f32x2 wx2[CIN / 2];
#pragma unroll
    for (int c = 0; c < CIN / 2; ++c) wx2[c] = (f32x2)(0.0f);

    const float* sdx = &s_dx[i * KNB];
    const float* sdy = &s_dy[i * KNB];
    const f32x2* sx2 = (const f32x2*)&s_x[i * KNB * CIN];

#pragma unroll
    for (int k = 0; k < KNB; ++k) {
        const float ddx = sdx[k] - mux;
        const float ddy = sdy[k] - muy;
        const float r2  = ddx * ddx + ddy * ddy;
        const float w   = EXP2F(fmaf(r2, c1, c2));   // fma + v_exp_f32, norm folded
        const f32x2 wv  = (f32x2)(w);
        const f32x2* xr = sx2 + k * (CIN / 2);
#pragma unroll
        for (int c = 0; c < CIN / 2; ++c) wx2[c] += wv * xr[c];   // packed fma
    }

    // acc as 4x float2; amp rows are 8B-aligned (AMP_STRIDE*4 and c*COUT*4 both 16B-mult).
    f32x2 acc2[COUT / 2];
#pragma unroll
    for (int o = 0; o < COUT / 2; ++o) acc2[o] = (f32x2)(0.0f);

    const float* arow = &s_amp[pd * AMP_STRIDE];
#pragma unroll
    for (int c = 0; c < CIN; ++c) {
        const float wc = (c & 1) ? wx2[c >> 1].y : wx2[c >> 1].x;
        const f32x2 wcv = (f32x2)(wc);
        const f32x2* ar = (const f32x2*)(arow + c * COUT);
#pragma unroll
        for (int o = 0; o < COUT / 2; ++o) acc2[o] += wcv * ar[o];  // packed fma
    }

    // out[((g*16)+pd)*8 + o] : 32 B/thread, contiguous across pd-threads.
    // NON-TEMPORAL: 134 MB of pure streaming writes must not thrash L2.
    float* op = out + ((base_g + i) * PD + pd) * COUT;
    f32x4 lo = { acc2[0].x, acc2[0].y, acc2[1].x, acc2[1].y };
    f32x4 hi = { acc2[2].x, acc2[2].y, acc2[3].x, acc2[3].y };
    __builtin_nontemporal_store(lo, (f32x4*)op);
    __builtin_nontemporal_store(hi, (f32x4*)(op + 4));
}

extern "C" void kernel_launch(void* const* d_in, const int* in_sizes, int n_in,
                              void* d_out, int out_size, void* d_ws, size_t ws_size,
                              hipStream_t stream) {
    const float* x     = (const float*)d_in[0];
    const float* dx    = (const float*)d_in[1];
    const float* dy    = (const float*)d_in[2];
    const int*   adj   = (const int*)  d_in[3];
    const float* phis  = (const float*)d_in[4];
    const float* dists = (const float*)d_in[5];
    const float* sigma = (const float*)d_in[6];
    const float* amp   = (const float*)d_in[7];
    float* out = (float*)d_out;

    const int total_pts = 2 * N_PTS;                 // B*N = 262144
    const int grid = total_pts / PTS_PER_BLK;        // 16384 blocks
    polnormal_kernel<<<grid, THREADS, 0, stream>>>(x, dx, dy, adj, phis, dists,
                                                   sigma, amp, out);
}

// Round 4
// 197.268 us; speedup vs baseline: 1.0728x; 1.0197x over previous
//
#include <hip/hip_runtime.h>
#include <math.h>

// Problem constants (fixed by the reference):
// B=2, N=131072 (=2^17), K=9, P=4, D=4, S=1, CI=8, CO=8
#define N_PTS 131072
#define KNB   9
#define PD    16          // P*D*S = 16 (p,d) cells per point
#define CIN   8
#define COUT  8
#define PTS_PER_BLK 32    // 2 points per compute thread (i and i+16)
#define THREADS 256
#define AMP_STRIDE 68     // 64 + 4 pad: 272 B = 17*16 B -> float4-aligned, 2-way only (free)

// Native clang vectors (NOT HIP_vector_type) — required by nontemporal builtins,
// and f32x2 arithmetic maps to v_pk_fma_f32 (packed fp32: 2 FMA / instr slot).
typedef float f32x2 __attribute__((ext_vector_type(2)));
typedef float f32x4 __attribute__((ext_vector_type(4)));

#if __has_builtin(__builtin_amdgcn_exp2f)
#define EXP2F(v) __builtin_amdgcn_exp2f(v)
#else
#define EXP2F(v) exp2f(v)
#endif

__global__ __launch_bounds__(THREADS) void polnormal_kernel(
    const float* __restrict__ x,      // (B, N, CI)
    const float* __restrict__ dx,     // (B, N, K)
    const float* __restrict__ dy,     // (B, N, K)
    const int*   __restrict__ adj,    // (N, K)
    const float* __restrict__ phis,  // (P,)
    const float* __restrict__ dists, // (D,)
    const float* __restrict__ sigma, // (S,) = (1,)
    const float* __restrict__ amp,   // (P, D, S, CI, CO) = (pd, c, o)
    float*       __restrict__ out)   // (B, N, P, D, S, CO)
{
    __shared__ float s_dd[PTS_PER_BLK * KNB * 2];    // interleaved (dx,dy) pairs -> ds_read_b64
    __shared__ float s_x[PTS_PER_BLK * KNB * CIN];   // [i][k][c]
    __shared__ float s_amp[PD * AMP_STRIDE];
    __shared__ float s_mu[2 * PD + 2];               // (mux,muy) per pd + c1,c2

    const int  tid    = threadIdx.x;
    const long base_g = (long)blockIdx.x * PTS_PER_BLK;   // flattened (b,n); 32 | N so no b-straddle
    const int  b      = (int)(base_g >> 17);              // N = 2^17
    const int  base_n = (int)(base_g & (N_PTS - 1));

    // --- Staging (all groups independent; one barrier at the end) ---

    // dx/dy: 288 floats each = 72 f32x4, NON-TEMPORAL (stream-once; keep L2 for x).
    // Interleave into s_dd so compute does one ds_read_b64 per (i,k).
    if (tid < 72) {
        f32x4 v = __builtin_nontemporal_load(&((const f32x4*)dx)[(long)blockIdx.x * 72 + tid]);
#pragma unroll
        for (int j = 0; j < 4; ++j) s_dd[(4 * tid + j) * 2] = v[j];
    } else if (tid < 144) {
        const int t = tid - 72;
        f32x4 v = __builtin_nontemporal_load(&((const f32x4*)dy)[(long)blockIdx.x * 72 + t]);
#pragma unroll
        for (int j = 0; j < 4; ++j) s_dd[(4 * t + j) * 2 + 1] = v[j];
    } else if (tid < 160) {
        // Per-pd constants: only 16 distinct values per block — compute once here
        // instead of in every compute thread.
        const int pdc = tid - 144;
        const int p = pdc >> 2, d = pdc & 3;
        float sn, cs;
        __sincosf(phis[p], &sn, &cs);
        const float dist = dists[d];
        s_mu[pdc * 2]     = cs * dist;
        s_mu[pdc * 2 + 1] = sn * dist;
    } else if (tid == 160) {
        // w = norm*exp(-0.5 r2/s2) == exp2(c1*r2 + c2)
        const float sig = fmaxf(sigma[0], 1e-10f);
        const float s2  = sig * sig;
        s_mu[32] = (-0.5f / s2) * 1.44269504088896340736f;
        s_mu[33] = -0.5f * __log2f(6.283185307179586f * s2);
    }

    // Amplitudes (4 KB, hot in L2 across all blocks): one float4 per thread.
    {
        const int pdc = tid >> 4;
        const int co  = (tid & 15) << 2;
        *(f32x4*)&s_amp[pdc * AMP_STRIDE + co] = ((const f32x4*)amp)[tid];
    }

    // Gather neighbor features: 288 rows, 1 thread/row (adj loaded once, stream-once
    // -> nontemporal; x rows stay cached — they're the only reused data).
    for (int t = tid; t < PTS_PER_BLK * KNB; t += THREADS) {
        const long row = (long)__builtin_nontemporal_load(&adj[(long)base_n * KNB + t]);
        const f32x4* src = (const f32x4*)(x + ((long)b * N_PTS + row) * CIN);
        f32x4* dst = (f32x4*)&s_x[t * CIN];
        dst[0] = src[0];
        dst[1] = src[1];
    }
    __syncthreads();   // single barrier: covers s_dd/s_amp/s_mu/s_x

    // --- Compute: thread (i, pd) handles points i and i+16 ---
    const int i  = tid >> 4;
    const int pd = tid & 15;

    const f32x2 mu  = *(const f32x2*)&s_mu[pd * 2];
    const float c1  = s_mu[32];
    const float c2  = s_mu[33];

    const f32x2* sddA = (const f32x2*)&s_dd[i * KNB * 2];
    const f32x2* sddB = (const f32x2*)&s_dd[(i + 16) * KNB * 2];
    const f32x2* sxA  = (const f32x2*)&s_x[i * KNB * CIN];
    const f32x2* sxB  = (const f32x2*)&s_x[(i + 16) * KNB * CIN];

    f32x2 wxA[CIN / 2], wxB[CIN / 2];
#pragma unroll
    for (int c = 0; c < CIN / 2; ++c) { wxA[c] = (f32x2)(0.0f); wxB[c] = (f32x2)(0.0f); }

#pragma unroll
    for (int k = 0; k < KNB; ++k) {
        const f32x2 ddA = sddA[k];           // (dx, dy) in one ds_read_b64
        const f32x2 ddB = sddB[k];
        const float dxA = ddA.x - mu.x, dyA = ddA.y - mu.y;
        const float dxB = ddB.x - mu.x, dyB = ddB.y - mu.y;
        const float r2A = dxA * dxA + dyA * dyA;
        const float r2B = dxB * dxB + dyB * dyB;
        const float wA  = EXP2F(fmaf(r2A, c1, c2));
        const float wB  = EXP2F(fmaf(r2B, c1, c2));
        const f32x2 wvA = (f32x2)(wA), wvB = (f32x2)(wB);
        const f32x2* xrA = sxA + k * (CIN / 2);
        const f32x2* xrB = sxB + k * (CIN / 2);
#pragma unroll
        for (int c = 0; c < CIN / 2; ++c) {
            wxA[c] += wvA * xrA[c];          // packed fma
            wxB[c] += wvB * xrB[c];
        }
    }

    // Matvec: amp row read ONCE from LDS, applied to both points.
    f32x2 accA[COUT / 2], accB[COUT / 2];
#pragma unroll
    for (int o = 0; o < COUT / 2; ++o) { accA[o] = (f32x2)(0.0f); accB[o] = (f32x2)(0.0f); }

    const float* arow = &s_amp[pd * AMP_STRIDE];
#pragma unroll
    for (int c = 0; c < CIN; ++c) {
        const f32x2* ar = (const f32x2*)(arow + c * COUT);
        const float wcA = (c & 1) ? wxA[c >> 1].y : wxA[c >> 1].x;
        const float wcB = (c & 1) ? wxB[c >> 1].y : wxB[c >> 1].x;
        const f32x2 wA2 = (f32x2)(wcA), wB2 = (f32x2)(wcB);
#pragma unroll
        for (int o = 0; o < COUT / 2; ++o) {
            accA[o] += wA2 * ar[o];          // packed fma
            accB[o] += wB2 * ar[o];
        }
    }

    // 32 B/thread/point, contiguous across pd-threads. NON-TEMPORAL (134 MB stream).
    float* opA = out + ((base_g + i) * PD + pd) * COUT;
    float* opB = out + ((base_g + i + 16) * PD + pd) * COUT;
    f32x4 loA = { accA[0].x, accA[0].y, accA[1].x, accA[1].y };
    f32x4 hiA = { accA[2].x, accA[2].y, accA[3].x, accA[3].y };
    f32x4 loB = { accB[0].x, accB[0].y, accB[1].x, accB[1].y };
    f32x4 hiB = { accB[2].x, accB[2].y, accB[3].x, accB[3].y };
    __builtin_nontemporal_store(loA, (f32x4*)opA);
    __builtin_nontemporal_store(hiA, (f32x4*)(opA + 4));
    __builtin_nontemporal_store(loB, (f32x4*)opB);
    __builtin_nontemporal_store(hiB, (f32x4*)(opB + 4));
}

extern "C" void kernel_launch(void* const* d_in, const int* in_sizes, int n_in,
                              void* d_out, int out_size, void* d_ws, size_t ws_size,
                              hipStream_t stream) {
    const float* x     = (const float*)d_in[0];
    const float* dx    = (const float*)d_in[1];
    const float* dy    = (const float*)d_in[2];
    const int*   adj   = (const int*)  d_in[3];
    const float* phis  = (const float*)d_in[4];
    const float* dists = (const float*)d_in[5];
    const float* sigma = (const float*)d_in[6];
    const float* amp   = (const float*)d_in[7];
    float* out = (float*)d_out;

    const int total_pts = 2 * N_PTS;                 // B*N = 262144
    const int grid = total_pts / PTS_PER_BLK;        // 8192 blocks
    polnormal_kernel<<<grid, THREADS, 0, stream>>>(x, dx, dy, adj, phis, dists,
                                                   sigma, amp, out);
}